// Round 1
// baseline (258.810 us; speedup 1.0000x reference)
//
#include <hip/hip_runtime.h>
#include <math.h>

// Problem constants (from setup_inputs): cost [8,1,48,128,240] f32, spg [8,9,512,960] f32
#define BB 8
#define DD 48
#define HH 128
#define WW 240
#define HW (HH * WW)
#define FH (4 * HH)   // 512
#define FW (4 * WW)   // 960
#define FHW (FH * FW)

// Stage 1: top-2 along D + softmax-of-2 weighted index sum -> disp4 [b,h,w]
// One thread per 4 consecutive w pixels (float4 loads per d).
__global__ __launch_bounds__(256) void disp4_kernel(const float* __restrict__ cost,
                                                    float* __restrict__ disp4) {
    int t = blockIdx.x * blockDim.x + threadIdx.x;
    const int WQ = WW / 4;                 // 60
    if (t >= BB * HH * WQ) return;
    int wq = t % WQ;
    int r  = t / WQ;
    int hy = r % HH;
    int b  = r / HH;

    const float* base = cost + (size_t)b * DD * HW + (size_t)hy * WW + wq * 4;

    float m1[4], m2[4], i1[4], i2[4];
#pragma unroll
    for (int k = 0; k < 4; ++k) { m1[k] = -INFINITY; m2[k] = -INFINITY; i1[k] = 0.f; i2[k] = 0.f; }

    for (int d = 0; d < DD; ++d) {
        float4 v4 = *reinterpret_cast<const float4*>(base + (size_t)d * HW);
        float v[4] = {v4.x, v4.y, v4.z, v4.w};
        float fd = (float)d;
#pragma unroll
        for (int k = 0; k < 4; ++k) {
            // strict > keeps lower index on ties, matching jax.lax.top_k
            if (v[k] > m1[k]) {
                m2[k] = m1[k]; i2[k] = i1[k];
                m1[k] = v[k];  i1[k] = fd;
            } else if (v[k] > m2[k]) {
                m2[k] = v[k];  i2[k] = fd;
            }
        }
    }

    float4 o;
    float out[4];
#pragma unroll
    for (int k = 0; k < 4; ++k) {
        // softmax over (m1,m2) with m1 >= m2: corr2 = e/(1+e), e = exp(m2-m1) <= 1
        float e = __expf(m2[k] - m1[k]);
        float s = e / (1.f + e);
        out[k] = i1[k] + (i2[k] - i1[k]) * s;
    }
    o.x = out[0]; o.y = out[1]; o.z = out[2]; o.w = out[3];
    *reinterpret_cast<float4*>(disp4 + (size_t)b * HW + (size_t)hy * WW + wq * 4) = o;
}

// Stage 2: softmax over 9 spg channels, weighted sum of 3x3 disp4 patch
// (nearest-4x-upsampled), *4. One thread per 4 consecutive output x
// (all 4 share the same coarse pixel -> one patch load per thread).
__global__ __launch_bounds__(256) void upfeat_kernel(const float* __restrict__ spg,
                                                     const float* __restrict__ disp4,
                                                     float* __restrict__ out) {
    int t = blockIdx.x * blockDim.x + threadIdx.x;
    const int XQ = FW / 4;                 // 240
    if (t >= BB * FH * XQ) return;
    int xq = t % XQ;                       // coarse x == fine x / 4
    int r  = t / XQ;
    int y  = r % FH;
    int b  = r / FH;
    int hy = y >> 2;

    // 3x3 patch of disp4, zero-padded
    float p[9];
#pragma unroll
    for (int i = 0; i < 3; ++i) {
#pragma unroll
        for (int j = 0; j < 3; ++j) {
            int cy = hy + i - 1;
            int cx = xq + j - 1;
            bool ok = (cy >= 0) & (cy < HH) & (cx >= 0) & (cx < WW);
            p[i * 3 + j] = ok ? disp4[(size_t)b * HW + (size_t)cy * WW + cx] : 0.f;
        }
    }

    const float* sp = spg + ((size_t)b * 9 * FH + (size_t)y) * FW + xq * 4;
    float s[9][4];
#pragma unroll
    for (int c = 0; c < 9; ++c) {
        float4 v = *reinterpret_cast<const float4*>(sp + (size_t)c * FHW);
        s[c][0] = v.x; s[c][1] = v.y; s[c][2] = v.z; s[c][3] = v.w;
    }

    float o[4];
#pragma unroll
    for (int k = 0; k < 4; ++k) {
        float m = s[0][k];
#pragma unroll
        for (int c = 1; c < 9; ++c) m = fmaxf(m, s[c][k]);
        float num = 0.f, den = 0.f;
#pragma unroll
        for (int c = 0; c < 9; ++c) {
            float e = __expf(s[c][k] - m);
            num = fmaf(e, p[c], num);
            den += e;
        }
        o[k] = 4.f * num / den;
    }

    float4 ov; ov.x = o[0]; ov.y = o[1]; ov.z = o[2]; ov.w = o[3];
    *reinterpret_cast<float4*>(out + ((size_t)b * FH + (size_t)y) * FW + xq * 4) = ov;
}

extern "C" void kernel_launch(void* const* d_in, const int* in_sizes, int n_in,
                              void* d_out, int out_size, void* d_ws, size_t ws_size,
                              hipStream_t stream) {
    const float* cost = (const float*)d_in[0];
    const float* spg  = (const float*)d_in[1];
    float* outp  = (float*)d_out;
    float* disp4 = (float*)d_ws;           // needs BB*HH*WW*4 = 3.93 MB

    {
        int total = BB * HH * (WW / 4);    // 61440
        int blocks = (total + 255) / 256;
        disp4_kernel<<<blocks, 256, 0, stream>>>(cost, disp4);
    }
    {
        int total = BB * FH * (FW / 4);    // 983040
        int blocks = (total + 255) / 256;
        upfeat_kernel<<<blocks, 256, 0, stream>>>(spg, disp4, outp);
    }
}

// Round 3
// 218.429 us; speedup vs baseline: 1.1849x; 1.1849x over previous
//
#include <hip/hip_runtime.h>
#include <math.h>

// Problem constants: cost [8,1,48,128,240] f32, spg [8,9,512,960] f32
#define BB 8
#define DD 48
#define HH 128
#define WW 240
#define HW (HH * WW)
#define FH (4 * HH)   // 512
#define FW (4 * WW)   // 960
#define FHW (FH * FW)

// clang-native vector types (HIP float2/float4 are classes -> rejected by
// __builtin_nontemporal_*)
typedef float vf2 __attribute__((ext_vector_type(2)));
typedef float vf4 __attribute__((ext_vector_type(4)));

// Stage 1: top-2 along D + softmax-of-2 weighted index -> disp4 [b,h,w]
// One thread per 2 consecutive w pixels (float2 loads), 480 blocks -> 30 waves/CU.
__global__ __launch_bounds__(256) void disp4_kernel(const float* __restrict__ cost,
                                                    float* __restrict__ disp4) {
    int t = blockIdx.x * blockDim.x + threadIdx.x;
    const int WQ = WW / 2;                 // 120
    if (t >= BB * HH * WQ) return;
    int wq = t % WQ;
    int r  = t / WQ;
    int hy = r % HH;
    int b  = r / HH;

    const float* base = cost + (size_t)b * DD * HW + (size_t)hy * WW + wq * 2;

    float m1[2], m2[2], i1[2], i2[2];
#pragma unroll
    for (int k = 0; k < 2; ++k) { m1[k] = -INFINITY; m2[k] = -INFINITY; i1[k] = 0.f; i2[k] = 0.f; }

#pragma unroll
    for (int dd = 0; dd < DD; dd += 8) {
        vf2 v[8];
#pragma unroll
        for (int u = 0; u < 8; ++u)
            v[u] = __builtin_nontemporal_load(
                reinterpret_cast<const vf2*>(base + (size_t)(dd + u) * HW));
#pragma unroll
        for (int u = 0; u < 8; ++u) {
            float fd = (float)(dd + u);
            float vv[2] = {v[u].x, v[u].y};
#pragma unroll
            for (int k = 0; k < 2; ++k) {
                // strict > keeps lower index on ties (matches jax.lax.top_k)
                bool g1 = vv[k] > m1[k];
                bool g2 = vv[k] > m2[k];
                m2[k] = g1 ? m1[k] : (g2 ? vv[k] : m2[k]);
                i2[k] = g1 ? i1[k] : (g2 ? fd    : i2[k]);
                m1[k] = g1 ? vv[k] : m1[k];
                i1[k] = g1 ? fd    : i1[k];
            }
        }
    }

    vf2 o;
#pragma unroll
    for (int k = 0; k < 2; ++k) {
        float e = __expf(m2[k] - m1[k]);   // e <= 1 since m1 >= m2
        float s = e / (1.f + e);
        o[k] = i1[k] + (i2[k] - i1[k]) * s;
    }
    *reinterpret_cast<vf2*>(disp4 + (size_t)b * HW + (size_t)hy * WW + wq * 2) = o;
}

// Stage 2: softmax over 9 spg channels, weighted sum of 3x3 disp4 patch
// (nearest-4x-upsampled), *4. One thread per 4 consecutive output x.
__global__ __launch_bounds__(256) void upfeat_kernel(const float* __restrict__ spg,
                                                     const float* __restrict__ disp4,
                                                     float* __restrict__ out) {
    int t = blockIdx.x * blockDim.x + threadIdx.x;
    const int XQ = FW / 4;                 // 240
    if (t >= BB * FH * XQ) return;
    int xq = t % XQ;                       // coarse x == fine x / 4
    int r  = t / XQ;
    int y  = r % FH;
    int b  = r / FH;
    int hy = y >> 2;

    // 3x3 patch of disp4, zero-padded (heavily reused across threads -> L1/L2)
    float p[9];
#pragma unroll
    for (int i = 0; i < 3; ++i) {
#pragma unroll
        for (int j = 0; j < 3; ++j) {
            int cy = hy + i - 1;
            int cx = xq + j - 1;
            bool ok = (cy >= 0) & (cy < HH) & (cx >= 0) & (cx < WW);
            p[i * 3 + j] = ok ? disp4[(size_t)b * HW + (size_t)cy * WW + cx] : 0.f;
        }
    }

    const float* sp = spg + ((size_t)b * 9 * FH + (size_t)y) * FW + xq * 4;
    float s[9][4];
#pragma unroll
    for (int c = 0; c < 9; ++c) {
        vf4 v = __builtin_nontemporal_load(
            reinterpret_cast<const vf4*>(sp + (size_t)c * FHW));
        s[c][0] = v.x; s[c][1] = v.y; s[c][2] = v.z; s[c][3] = v.w;
    }

    vf4 ov;
#pragma unroll
    for (int k = 0; k < 4; ++k) {
        float m = s[0][k];
#pragma unroll
        for (int c = 1; c < 9; ++c) m = fmaxf(m, s[c][k]);
        float num = 0.f, den = 0.f;
#pragma unroll
        for (int c = 0; c < 9; ++c) {
            float e = __expf(s[c][k] - m);
            num = fmaf(e, p[c], num);
            den += e;
        }
        ov[k] = 4.f * __fdividef(num, den);
    }

    __builtin_nontemporal_store(ov, reinterpret_cast<vf4*>(
        out + ((size_t)b * FH + (size_t)y) * FW + xq * 4));
}

extern "C" void kernel_launch(void* const* d_in, const int* in_sizes, int n_in,
                              void* d_out, int out_size, void* d_ws, size_t ws_size,
                              hipStream_t stream) {
    const float* cost = (const float*)d_in[0];
    const float* spg  = (const float*)d_in[1];
    float* outp  = (float*)d_out;
    float* disp4 = (float*)d_ws;           // needs BB*HH*WW*4 = 3.93 MB

    {
        int total = BB * HH * (WW / 2);    // 122880
        int blocks = (total + 255) / 256;  // 480
        disp4_kernel<<<blocks, 256, 0, stream>>>(cost, disp4);
    }
    {
        int total = BB * FH * (FW / 4);    // 983040
        int blocks = (total + 255) / 256;  // 3840
        upfeat_kernel<<<blocks, 256, 0, stream>>>(spg, disp4, outp);
    }
}